// Round 1
// baseline (1521.984 us; speedup 1.0000x reference)
//
#include <hip/hip_runtime.h>
#include <hip/hip_bf16.h>
#include <math.h>

#define NN    32768      // nodes
#define FIN   128        // input features
#define DD    512        // hidden dim
#define NDOCS 256        // documents
#define NE    262144     // edges
#define NPD   128        // nodes per doc (NN / NDOCS)

// ---------------------------------------------------------------------------
// degree init / count
// ---------------------------------------------------------------------------
__global__ __launch_bounds__(256) void init_deg(float* __restrict__ deg) {
    int i = blockIdx.x * 256 + threadIdx.x;
    if (i < NN) deg[i] = 1.0f;
}

__global__ __launch_bounds__(256) void count_deg(const int* __restrict__ dst, float* __restrict__ deg) {
    int e = blockIdx.x * 256 + threadIdx.x;
    if (e < NE) atomicAdd(&deg[dst[e]], 1.0f);
}

// ---------------------------------------------------------------------------
// dis = rsqrt(deg); exclusive scan of in-degree -> row_ptr, cursor
// single block of 1024 threads, 32 elements each
// ---------------------------------------------------------------------------
__global__ __launch_bounds__(1024) void scan_kernel(const float* __restrict__ deg, float* __restrict__ dis,
                                                    int* __restrict__ row_ptr, int* __restrict__ cursor) {
    __shared__ int part[1024];
    int t = threadIdx.x;
    const int CH = NN / 1024;   // 32
    int base = t * CH;
    int sum = 0;
    for (int i = 0; i < CH; ++i) {
        float d = deg[base + i];
        dis[base + i] = rsqrtf(d);
        sum += (int)d - 1;      // in-degree
    }
    part[t] = sum;
    __syncthreads();
    for (int off = 1; off < 1024; off <<= 1) {
        int v = (t >= off) ? part[t - off] : 0;
        __syncthreads();
        part[t] += v;
        __syncthreads();
    }
    int excl = (t == 0) ? 0 : part[t - 1];
    for (int i = 0; i < CH; ++i) {
        int c = (int)deg[base + i] - 1;
        row_ptr[base + i] = excl;
        cursor[base + i]  = excl;
        excl += c;
    }
    if (t == 1023) row_ptr[NN] = part[1023];
}

__global__ __launch_bounds__(256) void fill_csr(const int* __restrict__ src, const int* __restrict__ dst,
                                                const float* __restrict__ dis,
                                                int* __restrict__ cursor, int* __restrict__ csr_src,
                                                float* __restrict__ csr_norm) {
    int e = blockIdx.x * 256 + threadIdx.x;
    if (e < NE) {
        int d = dst[e];
        int s = src[e];
        int pos = atomicAdd(&cursor[d], 1);
        csr_src[pos]  = s;
        csr_norm[pos] = dis[s] * dis[d];
    }
}

// ---------------------------------------------------------------------------
// per-doc mean of attention_data (docs are contiguous 128-node segments)
// ---------------------------------------------------------------------------
__global__ __launch_bounds__(128) void doc_attn(const float* __restrict__ attn, float* __restrict__ dm) {
    int d = blockIdx.x;
    int t = threadIdx.x;
    float v = attn[d * NPD + t];
    #pragma unroll
    for (int off = 32; off >= 1; off >>= 1) v += __shfl_down(v, off);
    __shared__ float sm[2];
    if ((t & 63) == 0) sm[t >> 6] = v;
    __syncthreads();
    if (t == 0) dm[d] = (sm[0] + sm[1]) * (1.0f / (float)NPD);
}

// ---------------------------------------------------------------------------
// fp32 tiled GEMM: C[M x Dout] = A[M x K] @ W[K x Dout]  (+ optional bias+tanh)
// block = 256 threads, 64x64 tile, K-step 16, 4x4 micro-tile per thread
// ---------------------------------------------------------------------------
template <bool FUSE>
__global__ __launch_bounds__(256) void gemm64(const float* __restrict__ A, const float* __restrict__ W,
                                              const float* __restrict__ bias, float* __restrict__ C,
                                              int K, int Dout) {
    __shared__ float As[16][68];
    __shared__ float Bs[16][68];
    int tid = threadIdx.x;
    int m0 = blockIdx.y * 64;
    int n0 = blockIdx.x * 64;
    int ra = tid >> 2;            // 0..63: row in A tile
    int ca = (tid & 3) * 4;       // k offset of float4
    int rb = tid >> 4;            // 0..15: k row in B tile
    int cb = (tid & 15) * 4;      // n offset of float4
    int ty = tid >> 4;            // m group (x4)
    int tx = tid & 15;            // n group (x4)

    float acc[4][4] = {};
    for (int k0 = 0; k0 < K; k0 += 16) {
        float4 av = *(const float4*)(A + (size_t)(m0 + ra) * K + k0 + ca);
        float4 bv = *(const float4*)(W + (size_t)(k0 + rb) * Dout + n0 + cb);
        As[ca + 0][ra] = av.x;
        As[ca + 1][ra] = av.y;
        As[ca + 2][ra] = av.z;
        As[ca + 3][ra] = av.w;
        *(float4*)&Bs[rb][cb] = bv;
        __syncthreads();
        #pragma unroll
        for (int kk = 0; kk < 16; ++kk) {
            float4 a4 = *(const float4*)&As[kk][ty * 4];
            float4 b4 = *(const float4*)&Bs[kk][tx * 4];
            float a_[4] = {a4.x, a4.y, a4.z, a4.w};
            float b_[4] = {b4.x, b4.y, b4.z, b4.w};
            #pragma unroll
            for (int i = 0; i < 4; ++i)
                #pragma unroll
                for (int j = 0; j < 4; ++j)
                    acc[i][j] += a_[i] * b_[j];
        }
        __syncthreads();
    }
    float4 bb = make_float4(0.f, 0.f, 0.f, 0.f);
    if (FUSE) bb = *(const float4*)(bias + n0 + tx * 4);
    #pragma unroll
    for (int i = 0; i < 4; ++i) {
        int m = m0 + ty * 4 + i;
        float4 o;
        o.x = acc[i][0]; o.y = acc[i][1]; o.z = acc[i][2]; o.w = acc[i][3];
        if (FUSE) {
            o.x = tanhf(o.x + bb.x);
            o.y = tanhf(o.y + bb.y);
            o.z = tanhf(o.z + bb.z);
            o.w = tanhf(o.w + bb.w);
        }
        *(float4*)(C + (size_t)m * Dout + n0 + tx * 4) = o;
    }
}

// ---------------------------------------------------------------------------
// aggregation: out[n] = tanh( sum_e norm_e * hw[src_e] + dis[n]^2 * hw[n] + b )
// one block (128 threads) per dst node, float4 per thread over 512 cols
// ---------------------------------------------------------------------------
__global__ __launch_bounds__(128) void agg_kernel(const float* __restrict__ hw, const float* __restrict__ dis,
                                                  const int* __restrict__ row_ptr, const int* __restrict__ csr_src,
                                                  const float* __restrict__ csr_norm, const float* __restrict__ bias,
                                                  float* __restrict__ out) {
    int n = blockIdx.x;
    int t = threadIdx.x;           // float4 column index 0..127
    float dn = dis[n];
    float self_w = dn * dn;
    float4 v = *(const float4*)(hw + (size_t)n * DD + t * 4);
    float4 acc;
    acc.x = v.x * self_w; acc.y = v.y * self_w; acc.z = v.z * self_w; acc.w = v.w * self_w;
    int beg = row_ptr[n], end = row_ptr[n + 1];
    for (int e = beg; e < end; ++e) {
        int s = csr_src[e];
        float w = csr_norm[e];
        float4 u = *(const float4*)(hw + (size_t)s * DD + t * 4);
        acc.x += w * u.x; acc.y += w * u.y; acc.z += w * u.z; acc.w += w * u.w;
    }
    float4 bb = *(const float4*)(bias + t * 4);
    float4 o;
    o.x = tanhf(acc.x + bb.x);
    o.y = tanhf(acc.y + bb.y);
    o.z = tanhf(acc.z + bb.z);
    o.w = tanhf(acc.w + bb.w);
    *(float4*)(out + (size_t)n * DD + t * 4) = o;
}

// ---------------------------------------------------------------------------
// fc2: C2[N x 32] = tanh(H[N x 512] @ W2[512 x 32] + b2)
// block = 256 threads = 8 nodes x 32 outputs; rows staged in LDS
// ---------------------------------------------------------------------------
__global__ __launch_bounds__(256) void fc2_kernel(const float* __restrict__ H, const float* __restrict__ W2,
                                                  const float* __restrict__ b2, float* __restrict__ C2) {
    __shared__ float rows[8][DD];
    int blk = blockIdx.x;          // node base = blk*8
    int t = threadIdx.x;
    const float4* src = (const float4*)(H + (size_t)blk * 8 * DD);
    float4* dl = (float4*)(&rows[0][0]);
    #pragma unroll
    for (int i = 0; i < 4; ++i) dl[t + i * 256] = src[t + i * 256];
    __syncthreads();
    int g = t >> 5, j = t & 31;
    float sum = b2[j];
    const float* r = rows[g];
    for (int k = 0; k < DD; ++k) sum += r[k] * W2[k * 32 + j];
    C2[(size_t)(blk * 8 + g) * 32 + j] = tanhf(sum);
}

// ---------------------------------------------------------------------------
// fc3 + global mean pool: util[d] = mean_{n in doc d} (C2[n] . W3 + b3)
// ---------------------------------------------------------------------------
__global__ __launch_bounds__(128) void pool_kernel(const float* __restrict__ C2, const float* __restrict__ W3,
                                                   const float* __restrict__ b3, float* __restrict__ util) {
    int d = blockIdx.x;
    int t = threadIdx.x;
    int n = d * NPD + t;
    const float* c = C2 + (size_t)n * 32;
    float s = b3[0];
    #pragma unroll
    for (int j = 0; j < 32; ++j) s += c[j] * W3[j];
    #pragma unroll
    for (int off = 32; off >= 1; off >>= 1) s += __shfl_down(s, off);
    __shared__ float sm[2];
    if ((t & 63) == 0) sm[t >> 6] = s;
    __syncthreads();
    if (t == 0) util[d] = (sm[0] + sm[1]) * (1.0f / (float)NPD);
}

// ---------------------------------------------------------------------------
// final: out[i] = sigmoid((util[idx_b[i]] - util[idx_a[i]]) * dm[i^1])
// ---------------------------------------------------------------------------
__global__ __launch_bounds__(256) void final_kernel(const float* __restrict__ util, const float* __restrict__ dm,
                                                    const int* __restrict__ ia, const int* __restrict__ ib,
                                                    float* __restrict__ out) {
    int i = threadIdx.x;
    if (i < NDOCS) {
        float diff = util[ib[i]] - util[ia[i]];
        float a = dm[i ^ 1];
        out[i] = 1.0f / (1.0f + expf(-diff * a));
    }
}

// ---------------------------------------------------------------------------
// launch
// ---------------------------------------------------------------------------
extern "C" void kernel_launch(void* const* d_in, const int* in_sizes, int n_in,
                              void* d_out, int out_size, void* d_ws, size_t ws_size,
                              hipStream_t stream) {
    const float* x      = (const float*)d_in[0];
    const int*   ei     = (const int*)d_in[1];
    const int*   e_src  = ei;
    const int*   e_dst  = ei + NE;
    const float* attn   = (const float*)d_in[4];
    const int*   idx_a  = (const int*)d_in[5];
    const int*   idx_b  = (const int*)d_in[6];
    const float* W_in   = (const float*)d_in[7];
    const float* b_in   = (const float*)d_in[8];
    const float* W_hid  = (const float*)d_in[9];
    const float* b_hid  = (const float*)d_in[10];
    const float* W_out  = (const float*)d_in[11];
    const float* b_out  = (const float*)d_in[12];
    const float* W_fc1  = (const float*)d_in[13];
    const float* b_fc1  = (const float*)d_in[14];
    const float* W_fc2  = (const float*)d_in[15];
    const float* b_fc2  = (const float*)d_in[16];
    const float* W_fc3  = (const float*)d_in[17];
    const float* b_fc3  = (const float*)d_in[18];
    float* out = (float*)d_out;

    // workspace carve-up
    float* B0       = (float*)d_ws;                  // N*DD
    float* B1       = B0 + (size_t)NN * DD;          // N*DD
    float* C2       = B0;                            // N*32 (aliases B0; free after fc1)
    float* deg      = B1 + (size_t)NN * DD;          // N
    float* dis      = deg + NN;                      // N
    float* csr_norm = dis + NN;                      // E
    float* dm       = csr_norm + NE;                 // DOCS
    float* util     = dm + NDOCS;                    // DOCS
    int*   row_ptr  = (int*)(util + NDOCS);          // N+1
    int*   cursor   = row_ptr + (NN + 1);            // N
    int*   csr_src  = cursor + NN;                   // E

    // graph structure (rebuilt every call; inputs are restored each launch)
    init_deg<<<NN / 256, 256, 0, stream>>>(deg);
    count_deg<<<NE / 256, 256, 0, stream>>>(e_dst, deg);
    scan_kernel<<<1, 1024, 0, stream>>>(deg, dis, row_ptr, cursor);
    fill_csr<<<NE / 256, 256, 0, stream>>>(e_src, e_dst, dis, cursor, csr_src, csr_norm);
    doc_attn<<<NDOCS, 128, 0, stream>>>(attn, dm);

    dim3 gg(DD / 64, NN / 64);   // (8, 512)

    // layer 1: x @ W_in -> B1 ; agg -> B0
    gemm64<false><<<gg, 256, 0, stream>>>(x, W_in, nullptr, B1, FIN, DD);
    agg_kernel<<<NN, 128, 0, stream>>>(B1, dis, row_ptr, csr_src, csr_norm, b_in, B0);
    // layer 2: B0 @ W_hid -> B1 ; agg -> B0
    gemm64<false><<<gg, 256, 0, stream>>>(B0, W_hid, nullptr, B1, DD, DD);
    agg_kernel<<<NN, 128, 0, stream>>>(B1, dis, row_ptr, csr_src, csr_norm, b_hid, B0);
    // layer 3: B0 @ W_hid -> B1 ; agg -> B0
    gemm64<false><<<gg, 256, 0, stream>>>(B0, W_hid, nullptr, B1, DD, DD);
    agg_kernel<<<NN, 128, 0, stream>>>(B1, dis, row_ptr, csr_src, csr_norm, b_hid, B0);
    // layer 4: B0 @ W_out -> B1 ; agg -> B0
    gemm64<false><<<gg, 256, 0, stream>>>(B0, W_out, nullptr, B1, DD, DD);
    agg_kernel<<<NN, 128, 0, stream>>>(B1, dis, row_ptr, csr_src, csr_norm, b_out, B0);
    // fc1 (fused bias+tanh): B0 -> B1
    gemm64<true><<<gg, 256, 0, stream>>>(B0, W_fc1, b_fc1, B1, DD, DD);
    // fc2: B1 -> C2 (aliases B0)
    fc2_kernel<<<NN / 8, 256, 0, stream>>>(B1, W_fc2, b_fc2, C2);
    // fc3 + pool
    pool_kernel<<<NDOCS, 128, 0, stream>>>(C2, W_fc3, b_fc3, util);
    // readout
    final_kernel<<<1, 256, 0, stream>>>(util, dm, idx_a, idx_b, out);
}

// Round 2
// 623.479 us; speedup vs baseline: 2.4411x; 2.4411x over previous
//
#include <hip/hip_runtime.h>
#include <hip/hip_bf16.h>
#include <math.h>

#define NN    32768      // nodes
#define FIN   128        // input features
#define DD    512        // hidden dim
#define NDOCS 256        // documents
#define NE    262144     // edges
#define NPD   128        // nodes per doc

typedef __attribute__((ext_vector_type(8))) short s16x8;
typedef __attribute__((ext_vector_type(4))) float f32x4;

__device__ __forceinline__ unsigned short f2bf(float f) {
    union { float f; unsigned int u; } v; v.f = f;
    unsigned int r = (v.u + 0x7FFFu + ((v.u >> 16) & 1u)) >> 16;
    return (unsigned short)r;
}
__device__ __forceinline__ float bf2f(unsigned short h) {
    union { unsigned int u; float f; } v; v.u = ((unsigned int)h) << 16;
    return v.f;
}

__device__ __forceinline__ void gl2lds16(const void* g, void* l) {
    __builtin_amdgcn_global_load_lds(
        (const __attribute__((address_space(1))) int*)g,
        (__attribute__((address_space(3))) int*)l, 16, 0, 0);
}

// ---------------------------------------------------------------------------
// graph structure build (unchanged from round 1)
// ---------------------------------------------------------------------------
__global__ __launch_bounds__(256) void init_deg(float* __restrict__ deg) {
    int i = blockIdx.x * 256 + threadIdx.x;
    if (i < NN) deg[i] = 1.0f;
}

__global__ __launch_bounds__(256) void count_deg(const int* __restrict__ dst, float* __restrict__ deg) {
    int e = blockIdx.x * 256 + threadIdx.x;
    if (e < NE) atomicAdd(&deg[dst[e]], 1.0f);
}

__global__ __launch_bounds__(1024) void scan_kernel(const float* __restrict__ deg, float* __restrict__ dis,
                                                    int* __restrict__ row_ptr, int* __restrict__ cursor) {
    __shared__ int part[1024];
    int t = threadIdx.x;
    const int CH = NN / 1024;   // 32
    int base = t * CH;
    int sum = 0;
    for (int i = 0; i < CH; ++i) {
        float d = deg[base + i];
        dis[base + i] = rsqrtf(d);
        sum += (int)d - 1;
    }
    part[t] = sum;
    __syncthreads();
    for (int off = 1; off < 1024; off <<= 1) {
        int v = (t >= off) ? part[t - off] : 0;
        __syncthreads();
        part[t] += v;
        __syncthreads();
    }
    int excl = (t == 0) ? 0 : part[t - 1];
    for (int i = 0; i < CH; ++i) {
        int c = (int)deg[base + i] - 1;
        row_ptr[base + i] = excl;
        cursor[base + i]  = excl;
        excl += c;
    }
    if (t == 1023) row_ptr[NN] = part[1023];
}

__global__ __launch_bounds__(256) void fill_csr(const int* __restrict__ src, const int* __restrict__ dst,
                                                const float* __restrict__ dis,
                                                int* __restrict__ cursor, int* __restrict__ csr_src,
                                                float* __restrict__ csr_norm) {
    int e = blockIdx.x * 256 + threadIdx.x;
    if (e < NE) {
        int d = dst[e];
        int s = src[e];
        int pos = atomicAdd(&cursor[d], 1);
        csr_src[pos]  = s;
        csr_norm[pos] = dis[s] * dis[d];
    }
}

__global__ __launch_bounds__(128) void doc_attn(const float* __restrict__ attn, float* __restrict__ dm) {
    int d = blockIdx.x;
    int t = threadIdx.x;
    float v = attn[d * NPD + t];
    #pragma unroll
    for (int off = 32; off >= 1; off >>= 1) v += __shfl_down(v, off);
    __shared__ float sm[2];
    if ((t & 63) == 0) sm[t >> 6] = v;
    __syncthreads();
    if (t == 0) dm[d] = (sm[0] + sm[1]) * (1.0f / (float)NPD);
}

// ---------------------------------------------------------------------------
// conversions: x -> bf16, W[KxN] -> Wt[NxK] bf16 (N always 512)
// ---------------------------------------------------------------------------
__global__ __launch_bounds__(256) void cvt_x(const float* __restrict__ x, unsigned short* __restrict__ xb) {
    int i = blockIdx.x * 256 + threadIdx.x;   // per 4 elements
    float4 v = ((const float4*)x)[i];
    ushort4 o;
    o.x = f2bf(v.x); o.y = f2bf(v.y); o.z = f2bf(v.z); o.w = f2bf(v.w);
    ((ushort4*)xb)[i] = o;
}

__global__ __launch_bounds__(256) void wt_cvt(const float* __restrict__ W, unsigned short* __restrict__ Wt, int K) {
    int idx = blockIdx.x * 256 + threadIdx.x;   // over K*512 elements
    int k = idx >> 9;
    int n = idx & 511;
    Wt[(size_t)n * K + k] = f2bf(W[idx]);
}

// ---------------------------------------------------------------------------
// MFMA bf16 GEMM: C[MxN] = A[MxK] @ Bt[NxK]^T   (both row-major, contiguous K)
// 128x128 tile, BK=64, 256 thr (4 waves), each wave 64x64 via 4x4 16x16x32 MFMA
// global_load_lds width=16 staging; optional fused bias+tanh epilogue; bf16 out
// ---------------------------------------------------------------------------
template<bool FUSE>
__global__ __launch_bounds__(256) void mfma_gemm(const unsigned short* __restrict__ A,
                                                 const unsigned short* __restrict__ Bt,
                                                 const float* __restrict__ bias,
                                                 unsigned short* __restrict__ C,
                                                 int M, int N, int K) {
    __shared__ __align__(16) unsigned short As[128 * 64];
    __shared__ __align__(16) unsigned short Bs[128 * 64];
    int tid  = threadIdx.x;
    int lane = tid & 63;
    int wave = tid >> 6;
    int m0 = blockIdx.y * 128;
    int n0 = blockIdx.x * 128;
    int wm = (wave >> 1) * 64;
    int wn = (wave & 1) * 64;

    f32x4 zero = {0.f, 0.f, 0.f, 0.f};
    f32x4 acc[4][4];
    #pragma unroll
    for (int mi = 0; mi < 4; ++mi)
        #pragma unroll
        for (int ni = 0; ni < 4; ++ni) acc[mi][ni] = zero;

    // staging: chunk c = tid + i*256; row = c>>3, col = (c&7)*8 elements (16 B)
    int srow = tid >> 3;
    int scol = (tid & 7) * 8;
    const unsigned short* abase = A  + (size_t)(m0 + srow) * K + scol;
    const unsigned short* bbase = Bt + (size_t)(n0 + srow) * K + scol;

    for (int k0 = 0; k0 < K; k0 += 64) {
        __syncthreads();   // previous tile fully consumed
        #pragma unroll
        for (int i = 0; i < 4; ++i) {
            // wave-uniform LDS base; HW adds lane*16
            gl2lds16(abase + (size_t)i * 32 * K + k0, As + (size_t)(wave * 64 + i * 256) * 8);
            gl2lds16(bbase + (size_t)i * 32 * K + k0, Bs + (size_t)(wave * 64 + i * 256) * 8);
        }
        __syncthreads();   // drains vmcnt: staged tile visible
        #pragma unroll
        for (int ks = 0; ks < 2; ++ks) {
            s16x8 af[4], bfr[4];
            int kk = ks * 32 + (lane >> 4) * 8;
            int ar = wm + (lane & 15);
            int br = wn + (lane & 15);
            #pragma unroll
            for (int mi = 0; mi < 4; ++mi)
                af[mi] = *(const s16x8*)(As + (size_t)(ar + mi * 16) * 64 + kk);
            #pragma unroll
            for (int ni = 0; ni < 4; ++ni)
                bfr[ni] = *(const s16x8*)(Bs + (size_t)(br + ni * 16) * 64 + kk);
            #pragma unroll
            for (int mi = 0; mi < 4; ++mi)
                #pragma unroll
                for (int ni = 0; ni < 4; ++ni)
                    acc[mi][ni] = __builtin_amdgcn_mfma_f32_16x16x32_bf16(af[mi], bfr[ni], acc[mi][ni], 0, 0, 0);
        }
    }

    // epilogue: C/D layout col = lane&15, row = (lane>>4)*4 + reg
    int col = lane & 15;
    int rb  = (lane >> 4) * 4;
    #pragma unroll
    for (int ni = 0; ni < 4; ++ni) {
        int n = n0 + wn + ni * 16 + col;
        float bv = 0.f;
        if (FUSE) bv = bias[n];
        #pragma unroll
        for (int mi = 0; mi < 4; ++mi) {
            size_t base = (size_t)(m0 + wm + mi * 16 + rb) * N + n;
            #pragma unroll
            for (int r = 0; r < 4; ++r) {
                float v = acc[mi][ni][r];
                if (FUSE) v = tanhf(v + bv);
                C[base + (size_t)r * N] = f2bf(v);
            }
        }
    }
}

// ---------------------------------------------------------------------------
// aggregation (bf16 in/out): out[n] = tanh(sum_e norm*hw[src] + dis^2*hw[n] + b)
// one 64-lane wave per node, 4 nodes per 256-thread block; 16B loads per lane
// ---------------------------------------------------------------------------
__global__ __launch_bounds__(256) void agg_bf(const unsigned short* __restrict__ hw,
                                              const float* __restrict__ dis,
                                              const int* __restrict__ row_ptr,
                                              const int* __restrict__ csr_src,
                                              const float* __restrict__ csr_norm,
                                              const float* __restrict__ bias,
                                              unsigned short* __restrict__ out) {
    int n = blockIdx.x * 4 + (threadIdx.x >> 6);
    int lane = threadIdx.x & 63;
    int cb = lane * 8;
    float dn = dis[n];
    float sw = dn * dn;
    float acc[8];
    s16x8 v = *(const s16x8*)(hw + (size_t)n * DD + cb);
    #pragma unroll
    for (int j = 0; j < 8; ++j) acc[j] = bf2f((unsigned short)v[j]) * sw;
    int beg = row_ptr[n], end = row_ptr[n + 1];
    for (int e = beg; e < end; ++e) {
        int s = csr_src[e];
        float w = csr_norm[e];
        s16x8 u = *(const s16x8*)(hw + (size_t)s * DD + cb);
        #pragma unroll
        for (int j = 0; j < 8; ++j) acc[j] += w * bf2f((unsigned short)u[j]);
    }
    s16x8 o;
    #pragma unroll
    for (int j = 0; j < 8; ++j)
        o[j] = (short)f2bf(tanhf(acc[j] + bias[cb + j]));
    *(s16x8*)(out + (size_t)n * DD + cb) = o;
}

// ---------------------------------------------------------------------------
// fc2: C2[N x 32] = tanh(H[N x 512](bf16) @ W2[512 x 32] + b2)
// ---------------------------------------------------------------------------
__global__ __launch_bounds__(256) void fc2_bf(const unsigned short* __restrict__ H,
                                              const float* __restrict__ W2,
                                              const float* __restrict__ b2,
                                              float* __restrict__ C2) {
    __shared__ __align__(16) unsigned short rows[8 * DD];
    int blk = blockIdx.x;
    int t = threadIdx.x;
    const unsigned short* src = H + (size_t)blk * 8 * DD;
    #pragma unroll
    for (int i = 0; i < 2; ++i)
        *(s16x8*)(rows + (size_t)(t + i * 256) * 8) = *(const s16x8*)(src + (size_t)(t + i * 256) * 8);
    __syncthreads();
    int g = t >> 5, j = t & 31;
    float sum = b2[j];
    const unsigned short* r = rows + g * DD;
    for (int k = 0; k < DD; ++k) sum += bf2f(r[k]) * W2[k * 32 + j];
    C2[(size_t)(blk * 8 + g) * 32 + j] = tanhf(sum);
}

// ---------------------------------------------------------------------------
// fc3 + global mean pool
// ---------------------------------------------------------------------------
__global__ __launch_bounds__(128) void pool_kernel(const float* __restrict__ C2, const float* __restrict__ W3,
                                                   const float* __restrict__ b3, float* __restrict__ util) {
    int d = blockIdx.x;
    int t = threadIdx.x;
    int n = d * NPD + t;
    const float* c = C2 + (size_t)n * 32;
    float s = b3[0];
    #pragma unroll
    for (int j = 0; j < 32; ++j) s += c[j] * W3[j];
    #pragma unroll
    for (int off = 32; off >= 1; off >>= 1) s += __shfl_down(s, off);
    __shared__ float sm[2];
    if ((t & 63) == 0) sm[t >> 6] = s;
    __syncthreads();
    if (t == 0) util[d] = (sm[0] + sm[1]) * (1.0f / (float)NPD);
}

__global__ __launch_bounds__(256) void final_kernel(const float* __restrict__ util, const float* __restrict__ dm,
                                                    const int* __restrict__ ia, const int* __restrict__ ib,
                                                    float* __restrict__ out) {
    int i = threadIdx.x;
    if (i < NDOCS) {
        float diff = util[ib[i]] - util[ia[i]];
        float a = dm[i ^ 1];
        out[i] = 1.0f / (1.0f + expf(-diff * a));
    }
}

// ---------------------------------------------------------------------------
// launch
// ---------------------------------------------------------------------------
extern "C" void kernel_launch(void* const* d_in, const int* in_sizes, int n_in,
                              void* d_out, int out_size, void* d_ws, size_t ws_size,
                              hipStream_t stream) {
    const float* x      = (const float*)d_in[0];
    const int*   ei     = (const int*)d_in[1];
    const int*   e_src  = ei;
    const int*   e_dst  = ei + NE;
    const float* attn   = (const float*)d_in[4];
    const int*   idx_a  = (const int*)d_in[5];
    const int*   idx_b  = (const int*)d_in[6];
    const float* W_in   = (const float*)d_in[7];
    const float* b_in   = (const float*)d_in[8];
    const float* W_hid  = (const float*)d_in[9];
    const float* b_hid  = (const float*)d_in[10];
    const float* W_out  = (const float*)d_in[11];
    const float* b_out  = (const float*)d_in[12];
    const float* W_fc1  = (const float*)d_in[13];
    const float* b_fc1  = (const float*)d_in[14];
    const float* W_fc2  = (const float*)d_in[15];
    const float* b_fc2  = (const float*)d_in[16];
    const float* W_fc3  = (const float*)d_in[17];
    const float* b_fc3  = (const float*)d_in[18];
    float* out = (float*)d_out;

    // workspace carve-up (all sections 16B-aligned by construction)
    char* p = (char*)d_ws;
    unsigned short* hw_bf  = (unsigned short*)p; p += (size_t)NN * DD * 2;   // 32 MB
    unsigned short* h_bf   = (unsigned short*)p; p += (size_t)NN * DD * 2;   // 32 MB
    unsigned short* xb     = (unsigned short*)p; p += (size_t)NN * FIN * 2;  // 8 MB
    unsigned short* Wt_in  = (unsigned short*)p; p += (size_t)DD * FIN * 2;
    unsigned short* Wt_hid = (unsigned short*)p; p += (size_t)DD * DD * 2;
    unsigned short* Wt_out = (unsigned short*)p; p += (size_t)DD * DD * 2;
    unsigned short* Wt_fc1 = (unsigned short*)p; p += (size_t)DD * DD * 2;
    float* C2       = (float*)p; p += (size_t)NN * 32 * 4;                   // 4 MB
    float* deg      = (float*)p; p += (size_t)NN * 4;
    float* dis      = (float*)p; p += (size_t)NN * 4;
    float* csr_norm = (float*)p; p += (size_t)NE * 4;
    float* dm       = (float*)p; p += (size_t)NDOCS * 4;
    float* util     = (float*)p; p += (size_t)NDOCS * 4;
    int*   row_ptr  = (int*)p;   p += (size_t)(NN + 1) * 4 + 12;
    int*   cursor   = (int*)p;   p += (size_t)NN * 4;
    int*   csr_src  = (int*)p;

    // graph structure
    init_deg<<<NN / 256, 256, 0, stream>>>(deg);
    count_deg<<<NE / 256, 256, 0, stream>>>(e_dst, deg);
    scan_kernel<<<1, 1024, 0, stream>>>(deg, dis, row_ptr, cursor);
    fill_csr<<<NE / 256, 256, 0, stream>>>(e_src, e_dst, dis, cursor, csr_src, csr_norm);
    doc_attn<<<NDOCS, 128, 0, stream>>>(attn, dm);

    // dtype prep
    cvt_x<<<(NN * FIN / 4) / 256, 256, 0, stream>>>(x, xb);
    wt_cvt<<<(FIN * DD) / 256, 256, 0, stream>>>(W_in, Wt_in, FIN);
    wt_cvt<<<(DD * DD) / 256, 256, 0, stream>>>(W_hid, Wt_hid, DD);
    wt_cvt<<<(DD * DD) / 256, 256, 0, stream>>>(W_out, Wt_out, DD);
    wt_cvt<<<(DD * DD) / 256, 256, 0, stream>>>(W_fc1, Wt_fc1, DD);

    dim3 gg(DD / 128, NN / 128);   // (4, 256)

    // layer 1
    mfma_gemm<false><<<gg, 256, 0, stream>>>(xb, Wt_in, nullptr, hw_bf, NN, DD, FIN);
    agg_bf<<<NN / 4, 256, 0, stream>>>(hw_bf, dis, row_ptr, csr_src, csr_norm, b_in, h_bf);
    // layer 2
    mfma_gemm<false><<<gg, 256, 0, stream>>>(h_bf, Wt_hid, nullptr, hw_bf, NN, DD, DD);
    agg_bf<<<NN / 4, 256, 0, stream>>>(hw_bf, dis, row_ptr, csr_src, csr_norm, b_hid, h_bf);
    // layer 3
    mfma_gemm<false><<<gg, 256, 0, stream>>>(h_bf, Wt_hid, nullptr, hw_bf, NN, DD, DD);
    agg_bf<<<NN / 4, 256, 0, stream>>>(hw_bf, dis, row_ptr, csr_src, csr_norm, b_hid, h_bf);
    // layer 4
    mfma_gemm<false><<<gg, 256, 0, stream>>>(h_bf, Wt_out, nullptr, hw_bf, NN, DD, DD);
    agg_bf<<<NN / 4, 256, 0, stream>>>(hw_bf, dis, row_ptr, csr_src, csr_norm, b_out, h_bf);
    // fc1 (fused bias+tanh)
    mfma_gemm<true><<<gg, 256, 0, stream>>>(h_bf, Wt_fc1, b_fc1, hw_bf, NN, DD, DD);
    // fc2
    fc2_bf<<<NN / 8, 256, 0, stream>>>(hw_bf, W_fc2, b_fc2, C2);
    // fc3 + pool
    pool_kernel<<<NDOCS, 128, 0, stream>>>(C2, W_fc3, b_fc3, util);
    // readout
    final_kernel<<<1, 256, 0, stream>>>(util, dm, idx_a, idx_b, out);
}

// Round 3
// 536.636 us; speedup vs baseline: 2.8362x; 1.1618x over previous
//
#include <hip/hip_runtime.h>
#include <hip/hip_bf16.h>
#include <math.h>

#define NN    32768      // nodes
#define FIN   128        // input features
#define DD    512        // hidden dim
#define NDOCS 256        // documents
#define NE    262144     // edges
#define NPD   128        // nodes per doc

typedef __attribute__((ext_vector_type(8))) short s16x8;
typedef __attribute__((ext_vector_type(4))) float f32x4;

__device__ __forceinline__ unsigned short f2bf(float f) {
    union { float f; unsigned int u; } v; v.f = f;
    unsigned int r = (v.u + 0x7FFFu + ((v.u >> 16) & 1u)) >> 16;
    return (unsigned short)r;
}
__device__ __forceinline__ float bf2f(unsigned short h) {
    union { unsigned int u; float f; } v; v.u = ((unsigned int)h) << 16;
    return v.f;
}

__device__ __forceinline__ void gl2lds16(const void* g, void* l) {
    __builtin_amdgcn_global_load_lds(
        (const __attribute__((address_space(1))) int*)g,
        (__attribute__((address_space(3))) int*)l, 16, 0, 0);
}

// ---------------------------------------------------------------------------
// graph structure build
// ---------------------------------------------------------------------------
__global__ __launch_bounds__(256) void init_deg(int* __restrict__ deg) {
    int i = blockIdx.x * 256 + threadIdx.x;
    if (i < NN) deg[i] = 1;
}

__global__ __launch_bounds__(256) void count_deg(const int* __restrict__ dst, int* __restrict__ deg) {
    int e = blockIdx.x * 256 + threadIdx.x;
    if (e < NE) atomicAdd(&deg[dst[e]], 1);
}

__global__ __launch_bounds__(1024) void scan_kernel(const int* __restrict__ deg, float* __restrict__ dis,
                                                    int* __restrict__ row_ptr, int* __restrict__ cursor) {
    __shared__ int part[1024];
    int t = threadIdx.x;
    const int CH = NN / 1024;   // 32
    int base = t * CH;
    int sum = 0;
    for (int i = 0; i < CH; ++i) {
        int d = deg[base + i];
        dis[base + i] = rsqrtf((float)d);
        sum += d - 1;
    }
    part[t] = sum;
    __syncthreads();
    for (int off = 1; off < 1024; off <<= 1) {
        int v = (t >= off) ? part[t - off] : 0;
        __syncthreads();
        part[t] += v;
        __syncthreads();
    }
    int excl = (t == 0) ? 0 : part[t - 1];
    for (int i = 0; i < CH; ++i) {
        int c = deg[base + i] - 1;
        row_ptr[base + i] = excl;
        cursor[base + i]  = excl;
        excl += c;
    }
    if (t == 1023) row_ptr[NN] = part[1023];
}

__global__ __launch_bounds__(256) void fill_csr(const int* __restrict__ src, const int* __restrict__ dst,
                                                const float* __restrict__ dis,
                                                int* __restrict__ cursor, int* __restrict__ csr_src,
                                                float* __restrict__ csr_norm) {
    int e = blockIdx.x * 256 + threadIdx.x;
    if (e < NE) {
        int d = dst[e];
        int s = src[e];
        int pos = atomicAdd(&cursor[d], 1);
        csr_src[pos]  = s;
        csr_norm[pos] = dis[s] * dis[d];
    }
}

__global__ __launch_bounds__(128) void doc_attn(const float* __restrict__ attn, float* __restrict__ dm) {
    int d = blockIdx.x;
    int t = threadIdx.x;
    float v = attn[d * NPD + t];
    #pragma unroll
    for (int off = 32; off >= 1; off >>= 1) v += __shfl_down(v, off);
    __shared__ float sm[2];
    if ((t & 63) == 0) sm[t >> 6] = v;
    __syncthreads();
    if (t == 0) dm[d] = (sm[0] + sm[1]) * (1.0f / (float)NPD);
}

// ---------------------------------------------------------------------------
// conversions
// ---------------------------------------------------------------------------
__global__ __launch_bounds__(256) void cvt_x(const float* __restrict__ x, unsigned short* __restrict__ xb) {
    int i = blockIdx.x * 256 + threadIdx.x;   // per 4 elements
    float4 v = ((const float4*)x)[i];
    ushort4 o;
    o.x = f2bf(v.x); o.y = f2bf(v.y); o.z = f2bf(v.z); o.w = f2bf(v.w);
    ((ushort4*)xb)[i] = o;
}

// W[K x 512] -> Wt[512 x K] bf16
__global__ __launch_bounds__(256) void wt_cvt(const float* __restrict__ W, unsigned short* __restrict__ Wt, int K) {
    int idx = blockIdx.x * 256 + threadIdx.x;
    int k = idx >> 9;
    int n = idx & 511;
    Wt[(size_t)n * K + k] = f2bf(W[idx]);
}

// W_fc2[512 x 32] -> W2t[32 x 512] bf16
__global__ __launch_bounds__(256) void wt_cvt_fc2(const float* __restrict__ W, unsigned short* __restrict__ Wt) {
    int idx = blockIdx.x * 256 + threadIdx.x;   // over 512*32
    int k = idx >> 5;
    int n = idx & 31;
    Wt[(size_t)n * DD + k] = f2bf(W[idx]);
}

// ---------------------------------------------------------------------------
// MFMA bf16 GEMM: C[MxN] = A[MxK] @ Bt[NxK]^T (optional fused bias+tanh)
// ---------------------------------------------------------------------------
template<bool FUSE>
__global__ __launch_bounds__(256) void mfma_gemm(const unsigned short* __restrict__ A,
                                                 const unsigned short* __restrict__ Bt,
                                                 const float* __restrict__ bias,
                                                 unsigned short* __restrict__ C,
                                                 int M, int N, int K) {
    __shared__ __align__(16) unsigned short As[128 * 64];
    __shared__ __align__(16) unsigned short Bs[128 * 64];
    int tid  = threadIdx.x;
    int lane = tid & 63;
    int wave = tid >> 6;
    int m0 = blockIdx.y * 128;
    int n0 = blockIdx.x * 128;
    int wm = (wave >> 1) * 64;
    int wn = (wave & 1) * 64;

    f32x4 zero = {0.f, 0.f, 0.f, 0.f};
    f32x4 acc[4][4];
    #pragma unroll
    for (int mi = 0; mi < 4; ++mi)
        #pragma unroll
        for (int ni = 0; ni < 4; ++ni) acc[mi][ni] = zero;

    int srow = tid >> 3;
    int scol = (tid & 7) * 8;
    const unsigned short* abase = A  + (size_t)(m0 + srow) * K + scol;
    const unsigned short* bbase = Bt + (size_t)(n0 + srow) * K + scol;

    for (int k0 = 0; k0 < K; k0 += 64) {
        __syncthreads();
        #pragma unroll
        for (int i = 0; i < 4; ++i) {
            gl2lds16(abase + (size_t)i * 32 * K + k0, As + (size_t)(wave * 64 + i * 256) * 8);
            gl2lds16(bbase + (size_t)i * 32 * K + k0, Bs + (size_t)(wave * 64 + i * 256) * 8);
        }
        __syncthreads();
        #pragma unroll
        for (int ks = 0; ks < 2; ++ks) {
            s16x8 af[4], bfr[4];
            int kk = ks * 32 + (lane >> 4) * 8;
            int ar = wm + (lane & 15);
            int br = wn + (lane & 15);
            #pragma unroll
            for (int mi = 0; mi < 4; ++mi)
                af[mi] = *(const s16x8*)(As + (size_t)(ar + mi * 16) * 64 + kk);
            #pragma unroll
            for (int ni = 0; ni < 4; ++ni)
                bfr[ni] = *(const s16x8*)(Bs + (size_t)(br + ni * 16) * 64 + kk);
            #pragma unroll
            for (int mi = 0; mi < 4; ++mi)
                #pragma unroll
                for (int ni = 0; ni < 4; ++ni)
                    acc[mi][ni] = __builtin_amdgcn_mfma_f32_16x16x32_bf16(af[mi], bfr[ni], acc[mi][ni], 0, 0, 0);
        }
    }

    int col = lane & 15;
    int rb  = (lane >> 4) * 4;
    #pragma unroll
    for (int ni = 0; ni < 4; ++ni) {
        int n = n0 + wn + ni * 16 + col;
        float bv = 0.f;
        if (FUSE) bv = bias[n];
        #pragma unroll
        for (int mi = 0; mi < 4; ++mi) {
            size_t base = (size_t)(m0 + wm + mi * 16 + rb) * N + n;
            #pragma unroll
            for (int r = 0; r < 4; ++r) {
                float v = acc[mi][ni][r];
                if (FUSE) v = tanhf(v + bv);
                C[base + (size_t)r * N] = f2bf(v);
            }
        }
    }
}

// ---------------------------------------------------------------------------
// 512-wide aggregation (bf16 in/out), one wave per node, gather unrolled x2
// ---------------------------------------------------------------------------
__global__ __launch_bounds__(256) void agg_bf(const unsigned short* __restrict__ hw,
                                              const float* __restrict__ dis,
                                              const int* __restrict__ row_ptr,
                                              const int* __restrict__ csr_src,
                                              const float* __restrict__ csr_norm,
                                              const float* __restrict__ bias,
                                              unsigned short* __restrict__ out) {
    int n = blockIdx.x * 4 + (threadIdx.x >> 6);
    int lane = threadIdx.x & 63;
    int cb = lane * 8;
    float dn = dis[n];
    float sw = dn * dn;
    float acc[8];
    s16x8 v = *(const s16x8*)(hw + (size_t)n * DD + cb);
    #pragma unroll
    for (int j = 0; j < 8; ++j) acc[j] = bf2f((unsigned short)v[j]) * sw;
    int beg = row_ptr[n], end = row_ptr[n + 1];
    int e = beg;
    for (; e + 2 <= end; e += 2) {
        int s0 = csr_src[e], s1 = csr_src[e + 1];
        float w0 = csr_norm[e], w1 = csr_norm[e + 1];
        s16x8 u0 = *(const s16x8*)(hw + (size_t)s0 * DD + cb);
        s16x8 u1 = *(const s16x8*)(hw + (size_t)s1 * DD + cb);
        #pragma unroll
        for (int j = 0; j < 8; ++j) acc[j] += w0 * bf2f((unsigned short)u0[j]);
        #pragma unroll
        for (int j = 0; j < 8; ++j) acc[j] += w1 * bf2f((unsigned short)u1[j]);
    }
    if (e < end) {
        int s0 = csr_src[e];
        float w0 = csr_norm[e];
        s16x8 u0 = *(const s16x8*)(hw + (size_t)s0 * DD + cb);
        #pragma unroll
        for (int j = 0; j < 8; ++j) acc[j] += w0 * bf2f((unsigned short)u0[j]);
    }
    s16x8 o;
    #pragma unroll
    for (int j = 0; j < 8; ++j)
        o[j] = (short)f2bf(tanhf(acc[j] + bias[cb + j]));
    *(s16x8*)(out + (size_t)n * DD + cb) = o;
}

// ---------------------------------------------------------------------------
// layer-1 pre-aggregation on 128-wide x (bf16 in, bf16 out, fp32 accum)
// one wave per node, lane covers 2 cols (4 B)
// ---------------------------------------------------------------------------
__global__ __launch_bounds__(256) void agg_x(const unsigned short* __restrict__ xb,
                                             const float* __restrict__ dis,
                                             const int* __restrict__ row_ptr,
                                             const int* __restrict__ csr_src,
                                             const float* __restrict__ csr_norm,
                                             unsigned short* __restrict__ xagg) {
    int n = blockIdx.x * 4 + (threadIdx.x >> 6);
    int lane = threadIdx.x & 63;
    int cb = lane * 2;
    float dn = dis[n];
    float sw = dn * dn;
    unsigned int v = *(const unsigned int*)(xb + (size_t)n * FIN + cb);
    float a0 = bf2f((unsigned short)(v & 0xffffu)) * sw;
    float a1 = bf2f((unsigned short)(v >> 16)) * sw;
    int beg = row_ptr[n], end = row_ptr[n + 1];
    int e = beg;
    for (; e + 2 <= end; e += 2) {
        int s0 = csr_src[e], s1 = csr_src[e + 1];
        float w0 = csr_norm[e], w1 = csr_norm[e + 1];
        unsigned int u0 = *(const unsigned int*)(xb + (size_t)s0 * FIN + cb);
        unsigned int u1 = *(const unsigned int*)(xb + (size_t)s1 * FIN + cb);
        a0 += w0 * bf2f((unsigned short)(u0 & 0xffffu));
        a1 += w0 * bf2f((unsigned short)(u0 >> 16));
        a0 += w1 * bf2f((unsigned short)(u1 & 0xffffu));
        a1 += w1 * bf2f((unsigned short)(u1 >> 16));
    }
    if (e < end) {
        int s0 = csr_src[e];
        float w0 = csr_norm[e];
        unsigned int u0 = *(const unsigned int*)(xb + (size_t)s0 * FIN + cb);
        a0 += w0 * bf2f((unsigned short)(u0 & 0xffffu));
        a1 += w0 * bf2f((unsigned short)(u0 >> 16));
    }
    unsigned int o = (unsigned int)f2bf(a0) | ((unsigned int)f2bf(a1) << 16);
    *(unsigned int*)(xagg + (size_t)n * FIN + cb) = o;
}

// ---------------------------------------------------------------------------
// fused fc2+fc3+pool: one block per doc (128 nodes), MFMA 128x32, K=512
// util[d] = mean_n( tanh(H[n]@W2 + b2) . W3 ) + b3
// ---------------------------------------------------------------------------
__global__ __launch_bounds__(256) void fc23_pool(const unsigned short* __restrict__ H,
                                                 const unsigned short* __restrict__ W2t,
                                                 const float* __restrict__ b2,
                                                 const float* __restrict__ W3,
                                                 const float* __restrict__ b3,
                                                 float* __restrict__ util) {
    __shared__ __align__(16) unsigned short As[128 * 64];
    __shared__ __align__(16) unsigned short Bs[32 * 64];
    __shared__ float red[4];
    int d = blockIdx.x;
    int tid = threadIdx.x;
    int lane = tid & 63;
    int wave = tid >> 6;
    const unsigned short* A = H + (size_t)d * NPD * DD;

    f32x4 zero = {0.f, 0.f, 0.f, 0.f};
    f32x4 acc[2][2];
    #pragma unroll
    for (int mi = 0; mi < 2; ++mi)
        #pragma unroll
        for (int ni = 0; ni < 2; ++ni) acc[mi][ni] = zero;

    int srow = tid >> 3;
    int scol = (tid & 7) * 8;
    for (int k0 = 0; k0 < DD; k0 += 64) {
        __syncthreads();
        #pragma unroll
        for (int i = 0; i < 4; ++i)
            gl2lds16(A + (size_t)(srow + i * 32) * DD + k0 + scol,
                     As + (size_t)(wave * 64 + i * 256) * 8);
        gl2lds16(W2t + (size_t)srow * DD + k0 + scol, Bs + (size_t)(wave * 64) * 8);
        __syncthreads();
        #pragma unroll
        for (int ks = 0; ks < 2; ++ks) {
            int kk = ks * 32 + (lane >> 4) * 8;
            s16x8 af[2], bfr[2];
            #pragma unroll
            for (int mi = 0; mi < 2; ++mi)
                af[mi] = *(const s16x8*)(As + (size_t)(wave * 32 + mi * 16 + (lane & 15)) * 64 + kk);
            #pragma unroll
            for (int ni = 0; ni < 2; ++ni)
                bfr[ni] = *(const s16x8*)(Bs + (size_t)(ni * 16 + (lane & 15)) * 64 + kk);
            #pragma unroll
            for (int mi = 0; mi < 2; ++mi)
                #pragma unroll
                for (int ni = 0; ni < 2; ++ni)
                    acc[mi][ni] = __builtin_amdgcn_mfma_f32_16x16x32_bf16(af[mi], bfr[ni], acc[mi][ni], 0, 0, 0);
        }
    }

    // epilogue: tanh(+b2), dot W3, sum over everything
    int col = lane & 15;
    float part = 0.f;
    #pragma unroll
    for (int ni = 0; ni < 2; ++ni) {
        int j = ni * 16 + col;
        float b2v = b2[j];
        float w3v = W3[j];
        #pragma unroll
        for (int mi = 0; mi < 2; ++mi)
            #pragma unroll
            for (int r = 0; r < 4; ++r)
                part += tanhf(acc[mi][ni][r] + b2v) * w3v;
    }
    #pragma unroll
    for (int off = 32; off >= 1; off >>= 1) part += __shfl_down(part, off);
    if (lane == 0) red[wave] = part;
    __syncthreads();
    if (tid == 0) util[d] = (red[0] + red[1] + red[2] + red[3]) * (1.0f / (float)NPD) + b3[0];
}

__global__ __launch_bounds__(256) void final_kernel(const float* __restrict__ util, const float* __restrict__ dm,
                                                    const int* __restrict__ ia, const int* __restrict__ ib,
                                                    float* __restrict__ out) {
    int i = threadIdx.x;
    if (i < NDOCS) {
        float diff = util[ib[i]] - util[ia[i]];
        float a = dm[i ^ 1];
        out[i] = 1.0f / (1.0f + expf(-diff * a));
    }
}

// ---------------------------------------------------------------------------
// launch
// ---------------------------------------------------------------------------
extern "C" void kernel_launch(void* const* d_in, const int* in_sizes, int n_in,
                              void* d_out, int out_size, void* d_ws, size_t ws_size,
                              hipStream_t stream) {
    const float* x      = (const float*)d_in[0];
    const int*   ei     = (const int*)d_in[1];
    const int*   e_src  = ei;
    const int*   e_dst  = ei + NE;
    const float* attn   = (const float*)d_in[4];
    const int*   idx_a  = (const int*)d_in[5];
    const int*   idx_b  = (const int*)d_in[6];
    const float* W_in   = (const float*)d_in[7];
    const float* b_in   = (const float*)d_in[8];
    const float* W_hid  = (const float*)d_in[9];
    const float* b_hid  = (const float*)d_in[10];
    const float* W_out  = (const float*)d_in[11];
    const float* b_out  = (const float*)d_in[12];
    const float* W_fc1  = (const float*)d_in[13];
    const float* b_fc1  = (const float*)d_in[14];
    const float* W_fc2  = (const float*)d_in[15];
    const float* b_fc2  = (const float*)d_in[16];
    const float* W_fc3  = (const float*)d_in[17];
    const float* b_fc3  = (const float*)d_in[18];
    float* out = (float*)d_out;

    // workspace carve-up (16B-aligned by construction)
    char* p = (char*)d_ws;
    unsigned short* hw_bf  = (unsigned short*)p; p += (size_t)NN * DD * 2;   // 32 MB (also hosts xagg)
    unsigned short* h_bf   = (unsigned short*)p; p += (size_t)NN * DD * 2;   // 32 MB
    unsigned short* xb     = (unsigned short*)p; p += (size_t)NN * FIN * 2;  // 8 MB
    unsigned short* Wt_in  = (unsigned short*)p; p += (size_t)DD * FIN * 2;
    unsigned short* Wt_hid = (unsigned short*)p; p += (size_t)DD * DD * 2;
    unsigned short* Wt_out = (unsigned short*)p; p += (size_t)DD * DD * 2;
    unsigned short* Wt_fc1 = (unsigned short*)p; p += (size_t)DD * DD * 2;
    unsigned short* W2t    = (unsigned short*)p; p += (size_t)32 * DD * 2;
    int*   degi     = (int*)p;   p += (size_t)NN * 4;
    float* dis      = (float*)p; p += (size_t)NN * 4;
    float* csr_norm = (float*)p; p += (size_t)NE * 4;
    float* dm       = (float*)p; p += (size_t)NDOCS * 4;
    float* util     = (float*)p; p += (size_t)NDOCS * 4;
    int*   row_ptr  = (int*)p;   p += (size_t)(NN + 1) * 4 + 12;
    int*   cursor   = (int*)p;   p += (size_t)NN * 4;
    int*   csr_src  = (int*)p;
    unsigned short* xagg = hw_bf;   // 8 MB, aliases hw_bf (free before layer-1 GEMM writes h_bf)

    // graph structure
    init_deg<<<NN / 256, 256, 0, stream>>>(degi);
    count_deg<<<NE / 256, 256, 0, stream>>>(e_dst, degi);
    scan_kernel<<<1, 1024, 0, stream>>>(degi, dis, row_ptr, cursor);
    fill_csr<<<NE / 256, 256, 0, stream>>>(e_src, e_dst, dis, cursor, csr_src, csr_norm);
    doc_attn<<<NDOCS, 128, 0, stream>>>(attn, dm);

    // dtype prep
    cvt_x<<<(NN * FIN / 4) / 256, 256, 0, stream>>>(x, xb);
    wt_cvt<<<(FIN * DD) / 256, 256, 0, stream>>>(W_in, Wt_in, FIN);
    wt_cvt<<<(DD * DD) / 256, 256, 0, stream>>>(W_hid, Wt_hid, DD);
    wt_cvt<<<(DD * DD) / 256, 256, 0, stream>>>(W_out, Wt_out, DD);
    wt_cvt<<<(DD * DD) / 256, 256, 0, stream>>>(W_fc1, Wt_fc1, DD);
    wt_cvt_fc2<<<(DD * 32) / 256, 256, 0, stream>>>(W_fc2, W2t);

    dim3 gg(DD / 128, NN / 128);   // (4, 256)

    // layer 1: aggregate x first (A_norm x) @ W_in, fused bias+tanh
    agg_x<<<NN / 4, 256, 0, stream>>>(xb, dis, row_ptr, csr_src, csr_norm, xagg);
    mfma_gemm<true><<<gg, 256, 0, stream>>>(xagg, Wt_in, b_in, h_bf, NN, DD, FIN);
    // layer 2
    mfma_gemm<false><<<gg, 256, 0, stream>>>(h_bf, Wt_hid, nullptr, hw_bf, NN, DD, DD);
    agg_bf<<<NN / 4, 256, 0, stream>>>(hw_bf, dis, row_ptr, csr_src, csr_norm, b_hid, h_bf);
    // layer 3
    mfma_gemm<false><<<gg, 256, 0, stream>>>(h_bf, Wt_hid, nullptr, hw_bf, NN, DD, DD);
    agg_bf<<<NN / 4, 256, 0, stream>>>(hw_bf, dis, row_ptr, csr_src, csr_norm, b_hid, h_bf);
    // layer 4
    mfma_gemm<false><<<gg, 256, 0, stream>>>(h_bf, Wt_out, nullptr, hw_bf, NN, DD, DD);
    agg_bf<<<NN / 4, 256, 0, stream>>>(hw_bf, dis, row_ptr, csr_src, csr_norm, b_out, h_bf);
    // fc1 (fused bias+tanh)
    mfma_gemm<true><<<gg, 256, 0, stream>>>(h_bf, Wt_fc1, b_fc1, hw_bf, NN, DD, DD);
    // fc2+fc3+pool fused
    fc23_pool<<<NDOCS, 256, 0, stream>>>(hw_bf, W2t, b_fc2, W_fc3, b_fc3, util);
    // readout
    final_kernel<<<1, 256, 0, stream>>>(util, dm, idx_a, idx_b, out);
}